// Round 1
// baseline (695.930 us; speedup 1.0000x reference)
//
#include <hip/hip_runtime.h>

#define NN 10000      // nodes
// E read from in_sizes[1]/2 at runtime (expect 160000)

// ---------------------------------------------------------------------------
// CSR build kernels
// ---------------------------------------------------------------------------
__global__ __launch_bounds__(256) void zero_int(int* __restrict__ p, int n) {
    int i = blockIdx.x * 256 + threadIdx.x;
    if (i < n) p[i] = 0;
}

__global__ __launch_bounds__(256) void count_dst(const int* __restrict__ dst,
                                                 int* __restrict__ counts, int E) {
    int i = blockIdx.x * 256 + threadIdx.x;
    if (i < E) atomicAdd(&counts[dst[i]], 1);
}

__global__ __launch_bounds__(1024) void scan_build(const int* __restrict__ counts,
                                                   int* __restrict__ offsets,
                                                   int* __restrict__ cursor,
                                                   float* __restrict__ inv_cnt, int n) {
    __shared__ int part[1024];
    int tid = threadIdx.x;
    int per = (n + 1023) / 1024;
    int base = tid * per;
    int s = 0;
    for (int i = 0; i < per; i++) { int idx = base + i; if (idx < n) s += counts[idx]; }
    part[tid] = s;
    __syncthreads();
    for (int off = 1; off < 1024; off <<= 1) {
        int v = (tid >= off) ? part[tid - off] : 0;
        __syncthreads();
        part[tid] += v;
        __syncthreads();
    }
    int run = (tid > 0) ? part[tid - 1] : 0;
    for (int i = 0; i < per; i++) {
        int idx = base + i;
        if (idx < n) {
            int c = counts[idx];
            offsets[idx] = run;
            cursor[idx]  = run;
            inv_cnt[idx] = 1.0f / fmaxf((float)c, 1.0f);
            run += c;
        }
    }
}

__global__ __launch_bounds__(256) void scatter_edges(const int* __restrict__ src,
                                                     const int* __restrict__ dst,
                                                     int* __restrict__ cursor,
                                                     int* __restrict__ sorted_src, int E) {
    int i = blockIdx.x * 256 + threadIdx.x;
    if (i < E) {
        int p = atomicAdd(&cursor[dst[i]], 1);
        sorted_src[p] = src[i];
    }
}

// ---------------------------------------------------------------------------
// Fused dual GEMM (NT): C[m, 0:dout) = A[m,:]·Wl[n,:],  C[m, dout:2dout) = A·Wr
// A: [M,K] row-major, Wl/Wr: [dout,K] row-major. 128x128 tile, 8x8 micro-tile.
// BN=128 divides dout (512/256), so each block's n-tile lies fully in Wl or Wr.
// ---------------------------------------------------------------------------
__global__ __launch_bounds__(256) void gemm_xw(const float* __restrict__ A,
                                               const float* __restrict__ Bl,
                                               const float* __restrict__ Br,
                                               float* __restrict__ C,
                                               int M, int K, int dout) {
    const int BM = 128, BN = 128, BK = 16;
    __shared__ float As[BK][BM];   // k-major for vector LDS reads
    __shared__ float Bs[BK][BN];
    int tid = threadIdx.x;
    int tx = tid & 15, ty = tid >> 4;
    int bm = blockIdx.y * BM;
    int bn = blockIdx.x * BN;
    const float* Bsrc = (bn < dout) ? (Bl + (size_t)bn * K)
                                    : (Br + (size_t)(bn - dout) * K);
    int lrow = tid >> 2;         // 0..63
    int lk   = (tid & 3) << 2;   // 0,4,8,12

    float acc[8][8];
#pragma unroll
    for (int i = 0; i < 8; i++)
#pragma unroll
        for (int j = 0; j < 8; j++) acc[i][j] = 0.f;

    for (int k0 = 0; k0 < K; k0 += BK) {
#pragma unroll
        for (int h = 0; h < 2; ++h) {
            int r  = lrow + h * 64;
            int ga = bm + r; ga = (ga < M) ? ga : (M - 1);   // clamp; store is guarded
            float4 va = *(const float4*)(A + (size_t)ga * K + k0 + lk);
            As[lk + 0][r] = va.x; As[lk + 1][r] = va.y;
            As[lk + 2][r] = va.z; As[lk + 3][r] = va.w;
            float4 vb = *(const float4*)(Bsrc + (size_t)r * K + k0 + lk);
            Bs[lk + 0][r] = vb.x; Bs[lk + 1][r] = vb.y;
            Bs[lk + 2][r] = vb.z; Bs[lk + 3][r] = vb.w;
        }
        __syncthreads();
#pragma unroll
        for (int k = 0; k < BK; k++) {
            float a[8], b[8];
            *(float4*)(a)     = *(const float4*)&As[k][ty * 8];
            *(float4*)(a + 4) = *(const float4*)&As[k][ty * 8 + 4];
            *(float4*)(b)     = *(const float4*)&Bs[k][tx * 8];
            *(float4*)(b + 4) = *(const float4*)&Bs[k][tx * 8 + 4];
#pragma unroll
            for (int i = 0; i < 8; i++)
#pragma unroll
                for (int j = 0; j < 8; j++)
                    acc[i][j] = fmaf(a[i], b[j], acc[i][j]);
        }
        __syncthreads();
    }

    int Nn = 2 * dout;
#pragma unroll
    for (int i = 0; i < 8; i++) {
        int gr = bm + ty * 8 + i;
        if (gr < M) {
            float* Cp = C + (size_t)gr * Nn + bn + tx * 8;
            *(float4*)(Cp)     = make_float4(acc[i][0], acc[i][1], acc[i][2], acc[i][3]);
            *(float4*)(Cp + 4) = make_float4(acc[i][4], acc[i][5], acc[i][6], acc[i][7]);
        }
    }
}

// ---------------------------------------------------------------------------
// Per-node: mean-aggregate Y rows over CSR neighbors + Z + bias, L2-norm, ReLU.
// One wave per node; lane covers 4 consecutive floats per 256-wide chunk.
// ---------------------------------------------------------------------------
template <int DOUT>
__global__ __launch_bounds__(256) void agg_finalize(const float* __restrict__ YZ,
                                                    const int* __restrict__ offsets,
                                                    const int* __restrict__ counts,
                                                    const int* __restrict__ sorted_src,
                                                    const float* __restrict__ inv_cnt,
                                                    const float* __restrict__ bias,
                                                    float* __restrict__ xout, int n) {
    const int NCH = DOUT / 256;
    int wave = threadIdx.x >> 6;
    int lane = threadIdx.x & 63;
    int node = blockIdx.x * 4 + wave;
    if (node >= n) return;
    int start = offsets[node];
    int cnt   = counts[node];
    float inv = inv_cnt[node];

    float4 acc[NCH];
#pragma unroll
    for (int c = 0; c < NCH; c++) acc[c] = make_float4(0.f, 0.f, 0.f, 0.f);

    for (int e = 0; e < cnt; e++) {
        int src = sorted_src[start + e];
        const float* Yr = YZ + (size_t)src * (2 * DOUT);
#pragma unroll
        for (int c = 0; c < NCH; c++) {
            float4 v = *(const float4*)(Yr + c * 256 + lane * 4);
            acc[c].x += v.x; acc[c].y += v.y; acc[c].z += v.z; acc[c].w += v.w;
        }
    }

    const float* Zr = YZ + (size_t)node * (2 * DOUT) + DOUT;
    float4 val[NCH];
    float ss = 0.f;
#pragma unroll
    for (int c = 0; c < NCH; c++) {
        float4 z = *(const float4*)(Zr + c * 256 + lane * 4);
        float4 bb = *(const float4*)(bias + c * 256 + lane * 4);
        val[c].x = fmaf(acc[c].x, inv, z.x + bb.x);
        val[c].y = fmaf(acc[c].y, inv, z.y + bb.y);
        val[c].z = fmaf(acc[c].z, inv, z.z + bb.z);
        val[c].w = fmaf(acc[c].w, inv, z.w + bb.w);
        ss += val[c].x * val[c].x + val[c].y * val[c].y +
              val[c].z * val[c].z + val[c].w * val[c].w;
    }
#pragma unroll
    for (int m = 32; m >= 1; m >>= 1) ss += __shfl_xor(ss, m, 64);
    float scale = 1.0f / fmaxf(sqrtf(ss), 1e-12f);

    float* Op = xout + (size_t)node * DOUT;
#pragma unroll
    for (int c = 0; c < NCH; c++) {
        float4 o;
        o.x = fmaxf(val[c].x * scale, 0.f);
        o.y = fmaxf(val[c].y * scale, 0.f);
        o.z = fmaxf(val[c].z * scale, 0.f);
        o.w = fmaxf(val[c].w * scale, 0.f);
        *(float4*)(Op + c * 256 + lane * 4) = o;
    }
}

// ---------------------------------------------------------------------------
extern "C" void kernel_launch(void* const* d_in, const int* in_sizes, int n_in,
                              void* d_out, int out_size, void* d_ws, size_t ws_size,
                              hipStream_t stream) {
    const float* x    = (const float*)d_in[0];
    const int*   edge = (const int*)d_in[1];     // [2, E]: src row then dst row
    const float* Wl0  = (const float*)d_in[2];
    const float* b0   = (const float*)d_in[3];
    const float* Wr0  = (const float*)d_in[4];
    const float* Wl1  = (const float*)d_in[5];
    const float* b1   = (const float*)d_in[6];
    const float* Wr1  = (const float*)d_in[7];
    const float* Wl2  = (const float*)d_in[8];
    const float* b2   = (const float*)d_in[9];
    const float* Wr2  = (const float*)d_in[10];

    const int E = in_sizes[1] / 2;

    // Workspace layout (1KB-aligned slabs)
    char* ws = (char*)d_ws;
    int*   counts  = (int*)(ws + 0);
    int*   offsets = (int*)(ws + 40960);
    int*   cursor  = (int*)(ws + 81920);
    float* invc    = (float*)(ws + 122880);
    int*   sorted  = (int*)(ws + 163840);                   // E ints (640000 B)
    float* YZ      = (float*)(ws + 804864);                 // NN*1024 fp32 (40.96 MB)
    float* xbuf    = (float*)(ws + 804864 + 40960000);      // NN*512 fp32 (20.48 MB)

    // ---- CSR build (edges fixed within a call) ----
    zero_int<<<(NN + 255) / 256, 256, 0, stream>>>(counts, NN);
    count_dst<<<(E + 255) / 256, 256, 0, stream>>>(edge + E, counts, E);
    scan_build<<<1, 1024, 0, stream>>>(counts, offsets, cursor, invc, NN);
    scatter_edges<<<(E + 255) / 256, 256, 0, stream>>>(edge, edge + E, cursor, sorted, E);

    const int gy = (NN + 127) / 128;   // 79
    const int gb = (NN + 3) / 4;       // 2500

    // ---- layer 0: K=512, dout=512 ----
    gemm_xw<<<dim3(8, gy), 256, 0, stream>>>(x, Wl0, Wr0, YZ, NN, 512, 512);
    agg_finalize<512><<<gb, 256, 0, stream>>>(YZ, offsets, counts, sorted, invc, b0, xbuf, NN);
    // ---- layer 1: K=512, dout=512 ----
    gemm_xw<<<dim3(8, gy), 256, 0, stream>>>(xbuf, Wl1, Wr1, YZ, NN, 512, 512);
    agg_finalize<512><<<gb, 256, 0, stream>>>(YZ, offsets, counts, sorted, invc, b1, xbuf, NN);
    // ---- layer 2: K=512, dout=256 ----
    gemm_xw<<<dim3(4, gy), 256, 0, stream>>>(xbuf, Wl2, Wr2, YZ, NN, 512, 256);
    agg_finalize<256><<<gb, 256, 0, stream>>>(YZ, offsets, counts, sorted, invc, b2,
                                              (float*)d_out, NN);
}

// Round 3
// 333.043 us; speedup vs baseline: 2.0896x; 2.0896x over previous
//
#include <hip/hip_runtime.h>

#define NN 10000      // nodes

typedef __attribute__((ext_vector_type(8))) short short8;
typedef __attribute__((ext_vector_type(4))) float f32x4;

__device__ __forceinline__ ushort f2b(float f) {
    union { float f; uint32_t u; } v; v.f = f;
    uint32_t u = v.u;
    return (ushort)((u + 0x7fffu + ((u >> 16) & 1u)) >> 16);
}

// ---------------------------------------------------------------------------
// CSR build kernels (unchanged from round 1 — proven)
// ---------------------------------------------------------------------------
__global__ __launch_bounds__(256) void zero_int(int* __restrict__ p, int n) {
    int i = blockIdx.x * 256 + threadIdx.x;
    if (i < n) p[i] = 0;
}

__global__ __launch_bounds__(256) void count_dst(const int* __restrict__ dst,
                                                 int* __restrict__ counts, int E) {
    int i = blockIdx.x * 256 + threadIdx.x;
    if (i < E) atomicAdd(&counts[dst[i]], 1);
}

__global__ __launch_bounds__(1024) void scan_build(const int* __restrict__ counts,
                                                   int* __restrict__ offsets,
                                                   int* __restrict__ cursor,
                                                   float* __restrict__ inv_cnt, int n) {
    __shared__ int part[1024];
    int tid = threadIdx.x;
    int per = (n + 1023) / 1024;
    int base = tid * per;
    int s = 0;
    for (int i = 0; i < per; i++) { int idx = base + i; if (idx < n) s += counts[idx]; }
    part[tid] = s;
    __syncthreads();
    for (int off = 1; off < 1024; off <<= 1) {
        int v = (tid >= off) ? part[tid - off] : 0;
        __syncthreads();
        part[tid] += v;
        __syncthreads();
    }
    int run = (tid > 0) ? part[tid - 1] : 0;
    for (int i = 0; i < per; i++) {
        int idx = base + i;
        if (idx < n) {
            int c = counts[idx];
            offsets[idx] = run;
            cursor[idx]  = run;
            inv_cnt[idx] = 1.0f / fmaxf((float)c, 1.0f);
            run += c;
        }
    }
}

__global__ __launch_bounds__(256) void scatter_edges(const int* __restrict__ src,
                                                     const int* __restrict__ dst,
                                                     int* __restrict__ cursor,
                                                     int* __restrict__ sorted_src, int E) {
    int i = blockIdx.x * 256 + threadIdx.x;
    if (i < E) {
        int p = atomicAdd(&cursor[dst[i]], 1);
        sorted_src[p] = src[i];
    }
}

// ---------------------------------------------------------------------------
// fp32 -> bf16 conversion kernels
// ---------------------------------------------------------------------------
__global__ __launch_bounds__(256) void cvt_f2b(const float* __restrict__ in,
                                               ushort* __restrict__ out, int n4) {
    int i = blockIdx.x * 256 + threadIdx.x;
    if (i < n4) {
        float4 v = ((const float4*)in)[i];
        uint2 p;
        p.x = (uint)f2b(v.x) | ((uint)f2b(v.y) << 16);
        p.y = (uint)f2b(v.z) | ((uint)f2b(v.w) << 16);
        ((uint2*)out)[i] = p;
    }
}

// concat [Wl; Wr] -> bf16 [2*dout, K], K = 512
__global__ __launch_bounds__(256) void cvt_wcat(const float* __restrict__ Wl,
                                                const float* __restrict__ Wr,
                                                ushort* __restrict__ out,
                                                int dout, int n4) {
    int i = blockIdx.x * 256 + threadIdx.x;
    if (i >= n4) return;
    int idx = i * 4;
    int row = idx >> 9;          // K = 512
    int col = idx & 511;
    const float* src = (row < dout) ? (Wl + (size_t)row * 512 + col)
                                    : (Wr + (size_t)(row - dout) * 512 + col);
    float4 v = *(const float4*)src;
    uint2 p;
    p.x = (uint)f2b(v.x) | ((uint)f2b(v.y) << 16);
    p.y = (uint)f2b(v.z) | ((uint)f2b(v.w) << 16);
    *(uint2*)(out + idx) = p;
}

// ---------------------------------------------------------------------------
// bf16 MFMA NT-GEMM: C[M,Nn] fp32 = A[M,K] * B[Nn,K]^T, both bf16 row-major.
// 128x128 block tile, BK=32, 4 waves in 2x2, each wave 4x4 grid of 16x16x32.
// global_load_lds width-16 staging; LDS slot XOR-swizzle (koff ^ ((row>>1)&3))
// so fragment ds_read_b128s are <=2-way bank-aliased (free per m136).
// ---------------------------------------------------------------------------
__global__ __launch_bounds__(256) void gemm_mfma(const ushort* __restrict__ A,
                                                 const ushort* __restrict__ B,
                                                 float* __restrict__ C,
                                                 int M, int K, int Nn) {
    __shared__ ushort Asl[128 * 32];   // 8 KB
    __shared__ ushort Bsl[128 * 32];   // 8 KB
    const int tid  = threadIdx.x;
    const int w    = tid >> 6;
    const int lane = tid & 63;
    const int bm = blockIdx.y * 128, bn = blockIdx.x * 128;
    const int wm = (w & 1) * 64, wn = (w >> 1) * 64;
    const int row16 = lane & 15, q = lane >> 4;

    f32x4 acc[4][4];
#pragma unroll
    for (int i = 0; i < 4; i++)
#pragma unroll
        for (int j = 0; j < 4; j++) acc[i][j] = (f32x4){0.f, 0.f, 0.f, 0.f};

    const int sc_r = lane >> 2;      // row within 16-row chunk
    const int sc_s = lane & 3;       // physical 16B slot
    const int koff = sc_s ^ ((sc_r >> 1) & 3);   // logical k-offset for this slot

    // fragment LDS offsets (ushort units); swz depends only on row16 here
    const int swz = (row16 >> 1) & 3;

    for (int k0 = 0; k0 < K; k0 += 32) {
        if (w < 2) {
#pragma unroll
            for (int c = 0; c < 4; c++) {
                int chunk = w * 4 + c;                 // 0..7
                int rloc  = chunk * 16 + sc_r;         // 0..127
                int grow  = bm + rloc; grow = grow < M ? grow : M - 1;
                const ushort* gp = A + (size_t)grow * K + k0 + koff * 8;
                __builtin_amdgcn_global_load_lds(
                    (const __attribute__((address_space(1))) uint32_t*)gp,
                    (__attribute__((address_space(3))) uint32_t*)&Asl[chunk * 512],
                    16, 0, 0);
            }
        } else {
#pragma unroll
            for (int c = 0; c < 4; c++) {
                int chunk = (w - 2) * 4 + c;           // 0..7
                int rloc  = chunk * 16 + sc_r;
                const ushort* gp = B + (size_t)(bn + rloc) * K + k0 + koff * 8;
                __builtin_amdgcn_global_load_lds(
                    (const __attribute__((address_space(1))) uint32_t*)gp,
                    (__attribute__((address_space(3))) uint32_t*)&Bsl[chunk * 512],
                    16, 0, 0);
            }
        }
        __syncthreads();

        short8 af[4], bfr[4];
#pragma unroll
        for (int i = 0; i < 4; i++) {
            int r  = wm + i * 16 + row16;
            int s  = q ^ swz;
            af[i]  = *(const short8*)&Asl[r * 32 + s * 8];
            int rn = wn + i * 16 + row16;
            bfr[i] = *(const short8*)&Bsl[rn * 32 + s * 8];
        }
#pragma unroll
        for (int i = 0; i < 4; i++)
#pragma unroll
            for (int j = 0; j < 4; j++)
                acc[i][j] = __builtin_amdgcn_mfma_f32_16x16x32_bf16(
                    af[i], bfr[j], acc[i][j], 0, 0, 0);
        __syncthreads();
    }

    // C/D layout: col = lane&15, row = (lane>>4)*4 + reg  [m89-verified]
#pragma unroll
    for (int i = 0; i < 4; i++) {
#pragma unroll
        for (int r2 = 0; r2 < 4; r2++) {
            int row = bm + wm + i * 16 + q * 4 + r2;
            if (row < M) {
                float* Cp = C + (size_t)row * Nn + bn + wn + row16;
#pragma unroll
                for (int j = 0; j < 4; j++)
                    Cp[j * 16] = acc[i][j][r2];
            }
        }
    }
}

// ---------------------------------------------------------------------------
// Per-node: mean-aggregate Y rows over CSR neighbors + Z + bias, L2-norm, ReLU.
// One wave per node. Writes bf16 (next layer's A) or fp32 (final output).
// ---------------------------------------------------------------------------
template <int DOUT>
__global__ __launch_bounds__(256) void agg_finalize(const float* __restrict__ YZ,
                                                    const int* __restrict__ offsets,
                                                    const int* __restrict__ counts,
                                                    const int* __restrict__ sorted_src,
                                                    const float* __restrict__ inv_cnt,
                                                    const float* __restrict__ bias,
                                                    float* __restrict__ outf,
                                                    ushort* __restrict__ outb, int n) {
    const int NCH = DOUT / 256;
    int wave = threadIdx.x >> 6;
    int lane = threadIdx.x & 63;
    int node = blockIdx.x * 4 + wave;
    if (node >= n) return;
    int start = offsets[node];
    int cnt   = counts[node];
    float inv = inv_cnt[node];

    float4 acc[NCH];
#pragma unroll
    for (int c = 0; c < NCH; c++) acc[c] = make_float4(0.f, 0.f, 0.f, 0.f);

    for (int e = 0; e < cnt; e++) {
        int src = sorted_src[start + e];
        const float* Yr = YZ + (size_t)src * (2 * DOUT);
#pragma unroll
        for (int c = 0; c < NCH; c++) {
            float4 v = *(const float4*)(Yr + c * 256 + lane * 4);
            acc[c].x += v.x; acc[c].y += v.y; acc[c].z += v.z; acc[c].w += v.w;
        }
    }

    const float* Zr = YZ + (size_t)node * (2 * DOUT) + DOUT;
    float4 val[NCH];
    float ss = 0.f;
#pragma unroll
    for (int c = 0; c < NCH; c++) {
        float4 z  = *(const float4*)(Zr + c * 256 + lane * 4);
        float4 bb = *(const float4*)(bias + c * 256 + lane * 4);
        val[c].x = fmaf(acc[c].x, inv, z.x + bb.x);
        val[c].y = fmaf(acc[c].y, inv, z.y + bb.y);
        val[c].z = fmaf(acc[c].z, inv, z.z + bb.z);
        val[c].w = fmaf(acc[c].w, inv, z.w + bb.w);
        ss += val[c].x * val[c].x + val[c].y * val[c].y +
              val[c].z * val[c].z + val[c].w * val[c].w;
    }
#pragma unroll
    for (int m = 32; m >= 1; m >>= 1) ss += __shfl_xor(ss, m, 64);
    float scale = 1.0f / fmaxf(sqrtf(ss), 1e-12f);

    if (outb) {
        ushort* Op = outb + (size_t)node * DOUT;
#pragma unroll
        for (int c = 0; c < NCH; c++) {
            float ox = fmaxf(val[c].x * scale, 0.f);
            float oy = fmaxf(val[c].y * scale, 0.f);
            float oz = fmaxf(val[c].z * scale, 0.f);
            float ow = fmaxf(val[c].w * scale, 0.f);
            uint2 p;
            p.x = (uint)f2b(ox) | ((uint)f2b(oy) << 16);
            p.y = (uint)f2b(oz) | ((uint)f2b(ow) << 16);
            *(uint2*)(Op + c * 256 + lane * 4) = p;
        }
    } else {
        float* Op = outf + (size_t)node * DOUT;
#pragma unroll
        for (int c = 0; c < NCH; c++) {
            float4 o;
            o.x = fmaxf(val[c].x * scale, 0.f);
            o.y = fmaxf(val[c].y * scale, 0.f);
            o.z = fmaxf(val[c].z * scale, 0.f);
            o.w = fmaxf(val[c].w * scale, 0.f);
            *(float4*)(Op + c * 256 + lane * 4) = o;
        }
    }
}

// ---------------------------------------------------------------------------
extern "C" void kernel_launch(void* const* d_in, const int* in_sizes, int n_in,
                              void* d_out, int out_size, void* d_ws, size_t ws_size,
                              hipStream_t stream) {
    const float* x    = (const float*)d_in[0];
    const int*   edge = (const int*)d_in[1];     // [2, E]: src row then dst row
    const float* Wl0  = (const float*)d_in[2];
    const float* b0   = (const float*)d_in[3];
    const float* Wr0  = (const float*)d_in[4];
    const float* Wl1  = (const float*)d_in[5];
    const float* b1   = (const float*)d_in[6];
    const float* Wr1  = (const float*)d_in[7];
    const float* Wl2  = (const float*)d_in[8];
    const float* b2   = (const float*)d_in[9];
    const float* Wr2  = (const float*)d_in[10];

    const int E = in_sizes[1] / 2;

    // Workspace layout (bytes)
    char* ws = (char*)d_ws;
    int*    counts  = (int*)(ws + 0);             // 40000
    int*    offsets = (int*)(ws + 40960);
    int*    cursor  = (int*)(ws + 81920);
    float*  invc    = (float*)(ws + 122880);
    int*    sorted  = (int*)(ws + 163840);        // 640000
    ushort* Wc0     = (ushort*)(ws + 804864);     // 1024*512*2 = 1048576
    ushort* Wc1     = (ushort*)(ws + 1853440);    // 1048576
    ushort* Wc2     = (ushort*)(ws + 2902016);    // 512*512*2 = 524288
    ushort* xb      = (ushort*)(ws + 3426304);    // 10000*512*2 = 10240000
    float*  YZ      = (float*)(ws + 13666304);    // 10000*1024*4 = 40960000
    // end: 54626304 bytes

    // ---- CSR build ----
    zero_int<<<(NN + 255) / 256, 256, 0, stream>>>(counts, NN);
    count_dst<<<(E + 255) / 256, 256, 0, stream>>>(edge + E, counts, E);
    scan_build<<<1, 1024, 0, stream>>>(counts, offsets, cursor, invc, NN);
    scatter_edges<<<(E + 255) / 256, 256, 0, stream>>>(edge, edge + E, cursor, sorted, E);

    // ---- bf16 conversions ----
    cvt_f2b<<<(NN * 512 / 4 + 255) / 256, 256, 0, stream>>>(x, xb, NN * 512 / 4);
    cvt_wcat<<<(1024 * 512 / 4 + 255) / 256, 256, 0, stream>>>(Wl0, Wr0, Wc0, 512, 1024 * 512 / 4);
    cvt_wcat<<<(1024 * 512 / 4 + 255) / 256, 256, 0, stream>>>(Wl1, Wr1, Wc1, 512, 1024 * 512 / 4);
    cvt_wcat<<<(512 * 512 / 4 + 255) / 256, 256, 0, stream>>>(Wl2, Wr2, Wc2, 256, 512 * 512 / 4);

    const int gy = (NN + 127) / 128;   // 79
    const int gb = (NN + 3) / 4;       // 2500

    // ---- layer 0: K=512, Nn=1024 ----
    gemm_mfma<<<dim3(8, gy), 256, 0, stream>>>(xb, Wc0, YZ, NN, 512, 1024);
    agg_finalize<512><<<gb, 256, 0, stream>>>(YZ, offsets, counts, sorted, invc, b0,
                                              nullptr, xb, NN);
    // ---- layer 1: K=512, Nn=1024 ----
    gemm_mfma<<<dim3(8, gy), 256, 0, stream>>>(xb, Wc1, YZ, NN, 512, 1024);
    agg_finalize<512><<<gb, 256, 0, stream>>>(YZ, offsets, counts, sorted, invc, b1,
                                              nullptr, xb, NN);
    // ---- layer 2: K=512, Nn=512 ----
    gemm_mfma<<<dim3(4, gy), 256, 0, stream>>>(xb, Wc2, YZ, NN, 512, 512);
    agg_finalize<256><<<gb, 256, 0, stream>>>(YZ, offsets, counts, sorted, invc, b2,
                                              (float*)d_out, nullptr, NN);
}

// Round 4
// 276.623 us; speedup vs baseline: 2.5158x; 1.2040x over previous
//
#include <hip/hip_runtime.h>

#define NN 10000      // nodes

typedef __attribute__((ext_vector_type(8))) short short8;
typedef __attribute__((ext_vector_type(4))) float f32x4;

__device__ __forceinline__ ushort f2b(float f) {
    union { float f; uint32_t u; } v; v.f = f;
    uint32_t u = v.u;
    return (ushort)((u + 0x7fffu + ((u >> 16) & 1u)) >> 16);
}
__device__ __forceinline__ uint packbf(float a, float b) {
    return (uint)f2b(a) | ((uint)f2b(b) << 16);
}
__device__ __forceinline__ float blo(uint u) {
    union { uint u; float f; } v; v.u = u << 16; return v.f;
}
__device__ __forceinline__ float bhi(uint u) {
    union { uint u; float f; } v; v.u = u & 0xffff0000u; return v.f;
}

// ---------------------------------------------------------------------------
// CSR build kernels (proven)
// ---------------------------------------------------------------------------
__global__ __launch_bounds__(256) void zero_int(int* __restrict__ p, int n) {
    int i = blockIdx.x * 256 + threadIdx.x;
    if (i < n) p[i] = 0;
}

__global__ __launch_bounds__(256) void count_dst(const int* __restrict__ dst,
                                                 int* __restrict__ counts, int E) {
    int i = blockIdx.x * 256 + threadIdx.x;
    if (i < E) atomicAdd(&counts[dst[i]], 1);
}

__global__ __launch_bounds__(1024) void scan_build(const int* __restrict__ counts,
                                                   int* __restrict__ offsets,
                                                   int* __restrict__ cursor,
                                                   float* __restrict__ inv_cnt, int n) {
    __shared__ int part[1024];
    int tid = threadIdx.x;
    int per = (n + 1023) / 1024;
    int base = tid * per;
    int s = 0;
    for (int i = 0; i < per; i++) { int idx = base + i; if (idx < n) s += counts[idx]; }
    part[tid] = s;
    __syncthreads();
    for (int off = 1; off < 1024; off <<= 1) {
        int v = (tid >= off) ? part[tid - off] : 0;
        __syncthreads();
        part[tid] += v;
        __syncthreads();
    }
    int run = (tid > 0) ? part[tid - 1] : 0;
    for (int i = 0; i < per; i++) {
        int idx = base + i;
        if (idx < n) {
            int c = counts[idx];
            offsets[idx] = run;
            cursor[idx]  = run;
            inv_cnt[idx] = 1.0f / fmaxf((float)c, 1.0f);
            run += c;
        }
    }
}

__global__ __launch_bounds__(256) void scatter_edges(const int* __restrict__ src,
                                                     const int* __restrict__ dst,
                                                     int* __restrict__ cursor,
                                                     int* __restrict__ sorted_src, int E) {
    int i = blockIdx.x * 256 + threadIdx.x;
    if (i < E) {
        int p = atomicAdd(&cursor[dst[i]], 1);
        sorted_src[p] = src[i];
    }
}

// ---------------------------------------------------------------------------
// Conversions. xcat row layout: [0:512) = xagg (bf16), [512:1024) = x (bf16).
// ---------------------------------------------------------------------------
__global__ __launch_bounds__(256) void cvt_x(const float* __restrict__ in,
                                             ushort* __restrict__ xcat, int n4) {
    int i = blockIdx.x * 256 + threadIdx.x;
    if (i >= n4) return;
    int idx = i * 4;
    int node = idx >> 9;         // din = 512
    int col  = idx & 511;
    float4 v = *(const float4*)(in + (size_t)node * 512 + col);
    uint2 p;
    p.x = packbf(v.x, v.y);
    p.y = packbf(v.z, v.w);
    *(uint2*)(xcat + (size_t)node * 1024 + 512 + col) = p;
}

// Wcat[r][0:512) = Wl[r], [512:1024) = Wr[r]; bf16 [dout,1024] row-major.
__global__ __launch_bounds__(256) void cvt_w(const float* __restrict__ Wl,
                                             const float* __restrict__ Wr,
                                             ushort* __restrict__ out, int n4) {
    int i = blockIdx.x * 256 + threadIdx.x;
    if (i >= n4) return;
    int idx = i * 4;
    int row = idx >> 10;
    int col = idx & 1023;
    const float* src = (col < 512) ? (Wl + (size_t)row * 512 + col)
                                   : (Wr + (size_t)row * 512 + col - 512);
    float4 v = *(const float4*)src;
    uint2 p;
    p.x = packbf(v.x, v.y);
    p.y = packbf(v.z, v.w);
    *(uint2*)(out + idx) = p;
}

// ---------------------------------------------------------------------------
// Pre-GEMM mean aggregation over CSR neighbors, bf16 in / fp32 acc / bf16 out.
// One wave per node; lane covers 16B (8 bf16) of the 512-wide feature.
// Reads xcat right half (x), writes xcat left half (xagg). Edge loop x4.
// ---------------------------------------------------------------------------
__global__ __launch_bounds__(256) void agg_mean(ushort* __restrict__ xcat,
                                                const int* __restrict__ offsets,
                                                const int* __restrict__ counts,
                                                const int* __restrict__ sorted_src,
                                                const float* __restrict__ inv_cnt, int n) {
    int wave = threadIdx.x >> 6;
    int lane = threadIdx.x & 63;
    int node = blockIdx.x * 4 + wave;
    if (node >= n) return;
    int start = offsets[node];
    int cnt   = counts[node];
    float inv = inv_cnt[node];

    const uint* xr = (const uint*)xcat + 256;   // right half, uint units (row stride 512)
    int l4 = lane * 4;

    float acc[8];
#pragma unroll
    for (int k = 0; k < 8; k++) acc[k] = 0.f;

    int e = 0;
    for (; e + 4 <= cnt; e += 4) {
        int s0 = sorted_src[start + e + 0];
        int s1 = sorted_src[start + e + 1];
        int s2 = sorted_src[start + e + 2];
        int s3 = sorted_src[start + e + 3];
        uint4 v0 = *(const uint4*)(xr + (size_t)s0 * 512 + l4);
        uint4 v1 = *(const uint4*)(xr + (size_t)s1 * 512 + l4);
        uint4 v2 = *(const uint4*)(xr + (size_t)s2 * 512 + l4);
        uint4 v3 = *(const uint4*)(xr + (size_t)s3 * 512 + l4);
#define ACC8(v) do { \
        acc[0] += blo(v.x); acc[1] += bhi(v.x); \
        acc[2] += blo(v.y); acc[3] += bhi(v.y); \
        acc[4] += blo(v.z); acc[5] += bhi(v.z); \
        acc[6] += blo(v.w); acc[7] += bhi(v.w); } while (0)
        ACC8(v0); ACC8(v1); ACC8(v2); ACC8(v3);
    }
    for (; e < cnt; e++) {
        int s0 = sorted_src[start + e];
        uint4 v0 = *(const uint4*)(xr + (size_t)s0 * 512 + l4);
        ACC8(v0);
    }
#undef ACC8

    uint4 o;
    o.x = packbf(acc[0] * inv, acc[1] * inv);
    o.y = packbf(acc[2] * inv, acc[3] * inv);
    o.z = packbf(acc[4] * inv, acc[5] * inv);
    o.w = packbf(acc[6] * inv, acc[7] * inv);
    *(uint4*)(xcat + (size_t)node * 1024 + lane * 8) = o;
}

// ---------------------------------------------------------------------------
// bf16 MFMA NT-GEMM: C[M,Nn] fp32 = A[M,1024] * B[Nn,1024]^T, bf16 row-major.
// BM=64, BN=128, BK=32. 4 waves in 2x2 (32 rows x 64 cols each), acc[2][4].
// Staging: each wave issues 1 A-chunk + 2 B-chunks (16 rows x 32 cols, 1KB)
// via global_load_lds width-16. XOR slot swizzle (same algebra as R1-verified).
// ---------------------------------------------------------------------------
__global__ __launch_bounds__(256) void gemm_mfma(const ushort* __restrict__ A,
                                                 const ushort* __restrict__ B,
                                                 float* __restrict__ C,
                                                 int M, int Nn) {
    __shared__ ushort Asl[64 * 32];    // 4 KB
    __shared__ ushort Bsl[128 * 32];   // 8 KB
    const int tid  = threadIdx.x;
    const int w    = tid >> 6;
    const int lane = tid & 63;
    const int bm = blockIdx.y * 64, bn = blockIdx.x * 128;
    const int wm = (w & 1) * 32, wn = (w >> 1) * 64;
    const int row16 = lane & 15, q = lane >> 4;

    f32x4 acc[2][4];
#pragma unroll
    for (int i = 0; i < 2; i++)
#pragma unroll
        for (int j = 0; j < 4; j++) acc[i][j] = (f32x4){0.f, 0.f, 0.f, 0.f};

    const int sc_r = lane >> 2;                  // row within 16-row chunk
    const int sc_s = lane & 3;                   // physical 16B slot
    const int koff = sc_s ^ ((sc_r >> 1) & 3);   // logical k-chunk in this slot
    const int swz  = (row16 >> 1) & 3;

    for (int k0 = 0; k0 < 1024; k0 += 32) {
        // A chunk w: rows [w*16, w*16+16)
        {
            int rloc = w * 16 + sc_r;
            int grow = bm + rloc; grow = grow < M ? grow : M - 1;
            const ushort* gp = A + (size_t)grow * 1024 + k0 + koff * 8;
            __builtin_amdgcn_global_load_lds(
                (const __attribute__((address_space(1))) uint32_t*)gp,
                (__attribute__((address_space(3))) uint32_t*)&Asl[w * 512],
                16, 0, 0);
        }
        // B chunks 2w, 2w+1
#pragma unroll
        for (int c = 0; c < 2; c++) {
            int chunk = w * 2 + c;
            int rloc  = chunk * 16 + sc_r;
            const ushort* gp = B + (size_t)(bn + rloc) * 1024 + k0 + koff * 8;
            __builtin_amdgcn_global_load_lds(
                (const __attribute__((address_space(1))) uint32_t*)gp,
                (__attribute__((address_space(3))) uint32_t*)&Bsl[chunk * 512],
                16, 0, 0);
        }
        __syncthreads();

        short8 af[2], bfr[4];
        int s = q ^ swz;
#pragma unroll
        for (int i = 0; i < 2; i++) {
            int r = wm + i * 16 + row16;
            af[i] = *(const short8*)&Asl[r * 32 + s * 8];
        }
#pragma unroll
        for (int j = 0; j < 4; j++) {
            int rn = wn + j * 16 + row16;
            bfr[j] = *(const short8*)&Bsl[rn * 32 + s * 8];
        }
#pragma unroll
        for (int i = 0; i < 2; i++)
#pragma unroll
            for (int j = 0; j < 4; j++)
                acc[i][j] = __builtin_amdgcn_mfma_f32_16x16x32_bf16(
                    af[i], bfr[j], acc[i][j], 0, 0, 0);
        __syncthreads();
    }

    // C/D layout: col = lane&15, row = (lane>>4)*4 + reg  [m89-verified]
#pragma unroll
    for (int i = 0; i < 2; i++) {
#pragma unroll
        for (int r2 = 0; r2 < 4; r2++) {
            int row = bm + wm + i * 16 + q * 4 + r2;
            if (row < M) {
                float* Cp = C + (size_t)row * Nn + bn + wn + row16;
#pragma unroll
                for (int j = 0; j < 4; j++)
                    Cp[j * 16] = acc[i][j][r2];
            }
        }
    }
}

// ---------------------------------------------------------------------------
// Elementwise finalize: bias + L2-normalize + ReLU. One wave per node.
// Non-final: write bf16 into xcat right half. Final: write fp32 to d_out.
// ---------------------------------------------------------------------------
template <int DOUT, bool FINAL>
__global__ __launch_bounds__(256) void finalize(const float* __restrict__ Cbuf,
                                                const float* __restrict__ bias,
                                                ushort* __restrict__ xcat,
                                                float* __restrict__ outf, int n) {
    const int PL = DOUT / 64;    // floats per lane: 8 (512) or 4 (256)
    int wave = threadIdx.x >> 6;
    int lane = threadIdx.x & 63;
    int node = blockIdx.x * 4 + wave;
    if (node >= n) return;

    float v[PL];
    const float* Cp = Cbuf + (size_t)node * DOUT + lane * PL;
    const float* Bp = bias + lane * PL;
#pragma unroll
    for (int k = 0; k < PL; k += 4) {
        float4 c = *(const float4*)(Cp + k);
        float4 b = *(const float4*)(Bp + k);
        v[k + 0] = c.x + b.x; v[k + 1] = c.y + b.y;
        v[k + 2] = c.z + b.z; v[k + 3] = c.w + b.w;
    }
    float ss = 0.f;
#pragma unroll
    for (int k = 0; k < PL; k++) ss += v[k] * v[k];
#pragma unroll
    for (int m = 32; m >= 1; m >>= 1) ss += __shfl_xor(ss, m, 64);
    float scale = 1.0f / fmaxf(sqrtf(ss), 1e-12f);

    if (FINAL) {
        float* Op = outf + (size_t)node * DOUT + lane * PL;
#pragma unroll
        for (int k = 0; k < PL; k += 4) {
            float4 o;
            o.x = fmaxf(v[k + 0] * scale, 0.f);
            o.y = fmaxf(v[k + 1] * scale, 0.f);
            o.z = fmaxf(v[k + 2] * scale, 0.f);
            o.w = fmaxf(v[k + 3] * scale, 0.f);
            *(float4*)(Op + k) = o;
        }
    } else {
        // DOUT == 512 here: 8 bf16 = 16B per lane
        uint4 o;
        float r0 = fmaxf(v[0] * scale, 0.f), r1 = fmaxf(v[1] * scale, 0.f);
        float r2 = fmaxf(v[2] * scale, 0.f), r3 = fmaxf(v[3] * scale, 0.f);
        float r4 = fmaxf(v[4] * scale, 0.f), r5 = fmaxf(v[5] * scale, 0.f);
        float r6 = fmaxf(v[6] * scale, 0.f), r7 = fmaxf(v[7] * scale, 0.f);
        o.x = packbf(r0, r1); o.y = packbf(r2, r3);
        o.z = packbf(r4, r5); o.w = packbf(r6, r7);
        *(uint4*)(xcat + (size_t)node * 1024 + 512 + lane * 8) = o;
    }
}

// ---------------------------------------------------------------------------
extern "C" void kernel_launch(void* const* d_in, const int* in_sizes, int n_in,
                              void* d_out, int out_size, void* d_ws, size_t ws_size,
                              hipStream_t stream) {
    const float* x    = (const float*)d_in[0];
    const int*   edge = (const int*)d_in[1];     // [2, E]: src row then dst row
    const float* Wl0  = (const float*)d_in[2];
    const float* b0   = (const float*)d_in[3];
    const float* Wr0  = (const float*)d_in[4];
    const float* Wl1  = (const float*)d_in[5];
    const float* b1   = (const float*)d_in[6];
    const float* Wr1  = (const float*)d_in[7];
    const float* Wl2  = (const float*)d_in[8];
    const float* b2   = (const float*)d_in[9];
    const float* Wr2  = (const float*)d_in[10];

    const int E = in_sizes[1] / 2;

    // Workspace layout (bytes)
    char* ws = (char*)d_ws;
    int*    counts  = (int*)(ws + 0);              // 40000
    int*    offsets = (int*)(ws + 40960);
    int*    cursor  = (int*)(ws + 81920);
    float*  invc    = (float*)(ws + 122880);
    int*    sorted  = (int*)(ws + 163840);         // 640000
    ushort* Wc0     = (ushort*)(ws + 804864);      // 512*1024*2  = 1048576
    ushort* Wc1     = (ushort*)(ws + 1853440);     // 1048576
    ushort* Wc2     = (ushort*)(ws + 2902016);     // 256*1024*2  = 524288
    ushort* xcat    = (ushort*)(ws + 3426304);     // 10000*1024*2 = 20480000
    float*  Cbuf    = (float*)(ws + 23906304);     // 10000*512*4  = 20480000
    // end: 44386304 bytes

    // ---- CSR build ----
    zero_int<<<(NN + 255) / 256, 256, 0, stream>>>(counts, NN);
    count_dst<<<(E + 255) / 256, 256, 0, stream>>>(edge + E, counts, E);
    scan_build<<<1, 1024, 0, stream>>>(counts, offsets, cursor, invc, NN);
    scatter_edges<<<(E + 255) / 256, 256, 0, stream>>>(edge, edge + E, cursor, sorted, E);

    // ---- bf16 conversions ----
    cvt_x<<<(NN * 512 / 4 + 255) / 256, 256, 0, stream>>>(x, xcat, NN * 512 / 4);
    cvt_w<<<(512 * 1024 / 4 + 255) / 256, 256, 0, stream>>>(Wl0, Wr0, Wc0, 512 * 1024 / 4);
    cvt_w<<<(512 * 1024 / 4 + 255) / 256, 256, 0, stream>>>(Wl1, Wr1, Wc1, 512 * 1024 / 4);
    cvt_w<<<(256 * 1024 / 4 + 255) / 256, 256, 0, stream>>>(Wl2, Wr2, Wc2, 256 * 1024 / 4);

    const int gyM = (NN + 63) / 64;    // 157
    const int gb  = (NN + 3) / 4;      // 2500

    // ---- layer 0 ----
    agg_mean<<<gb, 256, 0, stream>>>(xcat, offsets, counts, sorted, invc, NN);
    gemm_mfma<<<dim3(4, gyM), 256, 0, stream>>>(xcat, Wc0, Cbuf, NN, 512);
    finalize<512, false><<<gb, 256, 0, stream>>>(Cbuf, b0, xcat, nullptr, NN);
    // ---- layer 1 ----
    agg_mean<<<gb, 256, 0, stream>>>(xcat, offsets, counts, sorted, invc, NN);
    gemm_mfma<<<dim3(4, gyM), 256, 0, stream>>>(xcat, Wc1, Cbuf, NN, 512);
    finalize<512, false><<<gb, 256, 0, stream>>>(Cbuf, b1, xcat, nullptr, NN);
    // ---- layer 2 ----
    agg_mean<<<gb, 256, 0, stream>>>(xcat, offsets, counts, sorted, invc, NN);
    gemm_mfma<<<dim3(2, gyM), 256, 0, stream>>>(xcat, Wc2, Cbuf, NN, 256);
    finalize<256, true><<<gb, 256, 0, stream>>>(Cbuf, b2, nullptr, (float*)d_out, NN);
}